// Round 4
// baseline (104.533 us; speedup 1.0000x reference)
//
#include <hip/hip_runtime.h>
#include <hip/hip_bf16.h>
#include <stdint.h>

#define LOG2E  1.4426950408889634f
#define LOG2E5 0.28853900817779268f   // 0.2 * LOG2E

typedef __attribute__((ext_vector_type(4))) float f4;
typedef __attribute__((ext_vector_type(4))) int   i4;
typedef __attribute__((ext_vector_type(8))) short s8;   // 8 x bf16
typedef __attribute__((ext_vector_type(4))) short s4;   // 4 x bf16

#if defined(__has_builtin)
# if __has_builtin(__builtin_amdgcn_exp2f)
#  define EXP2F(x) __builtin_amdgcn_exp2f(x)
# else
#  define EXP2F(x) exp2f(x)
# endif
#else
# define EXP2F(x) exp2f(x)
#endif

static __device__ __forceinline__ uint32_t fbits(float f) {
  union { float f; uint32_t u; } c; c.f = f; return c.u;
}
static __device__ __forceinline__ float ubits(uint32_t u) {
  union { uint32_t u; float f; } c; c.u = u; return c.f;
}
static __device__ __forceinline__ uint16_t bf16_rne(float f) {
  uint32_t b = fbits(f);
  b += 0x7FFFu + ((b >> 16) & 1u);
  return (uint16_t)(b >> 16);
}
static __device__ __forceinline__ float bf2f(uint16_t u) {
  return ubits(((uint32_t)u) << 16);
}
// order-preserving float->uint key (for atomicMax on floats)
static __device__ __forceinline__ uint32_t fkey(float f) {
  uint32_t u = fbits(f);
  return (u >> 31) ? ~u : (u | 0x80000000u);
}
static __device__ __forceinline__ float unkey(uint32_t k) {
  return ubits((k & 0x80000000u) ? (k ^ 0x80000000u) : ~k);
}

// ---- K1: W (H,256,64) f32 -> WT (H,64,256) bf16; init f2max keys ----
__global__ __launch_bounds__(256) void k_prep_wt(const float* __restrict__ W,
                                                 uint16_t* __restrict__ WT,
                                                 uint32_t* __restrict__ f2mkey) {
  if (blockIdx.x == 0 && threadIdx.x < 4) f2mkey[threadIdx.x] = 0u;
  int idx = (blockIdx.x * 256 + threadIdx.x) * 4;   // 65536 elems, grid 64
  f4 w = *(const f4*)(W + idx);
  int h = idx >> 14;
  int k = (idx >> 6) & 255;
  int o = idx & 63;
  uint16_t* base = WT + ((h << 6) + o) * 256 + k;
  base[0]   = bf16_rne(w.x);
  base[256] = bf16_rne(w.y);
  base[512] = bf16_rne(w.z);
  base[768] = bf16_rne(w.w);
}

// ------- K2: h = x @ W per head (MFMA), fused f1/f2 + f2max ---------------
// h stored directly in MFMA B-fragment order:
//   chunk idx = ((head*32 + j/128)*4 + (j/32)%4)*4 + cg, 512 shorts/chunk.
__global__ __launch_bounds__(256) void k_gemm_h(
    const float* __restrict__ x, const uint16_t* __restrict__ WT,
    const float* __restrict__ a,
    uint16_t* __restrict__ hTf, float* __restrict__ f1, float* __restrict__ f2,
    uint32_t* __restrict__ f2mkey) {
  const int N = 4096, K = 256;
  __shared__ uint16_t xs[16][264];
  int t = threadIdx.x;
  int i0 = blockIdx.x * 16;
  {
    int r = t >> 4, c = (t & 15) << 4;
    const float* src = x + (i0 + r) * K + c;
    union { uint16_t u[16]; s8 v[2]; } tmp;
    #pragma unroll
    for (int i = 0; i < 16; i += 4) {
      f4 v = *(const f4*)(src + i);
      tmp.u[i+0] = bf16_rne(v.x); tmp.u[i+1] = bf16_rne(v.y);
      tmp.u[i+2] = bf16_rne(v.z); tmp.u[i+3] = bf16_rne(v.w);
    }
    *(s8*)&xs[r][c]     = tmp.v[0];
    *(s8*)&xs[r][c + 8] = tmp.v[1];
  }
  __syncthreads();
  int wave = t >> 6, lane = t & 63, lr = lane & 15, lc = lane >> 4;
  f4 acc[4];
  #pragma unroll
  for (int cg = 0; cg < 4; ++cg) acc[cg] = (f4){0.f, 0.f, 0.f, 0.f};
  #pragma unroll
  for (int ks = 0; ks < 8; ++ks) {
    s8 af = *(const s8*)&xs[lr][ks * 32 + lc * 8];
    #pragma unroll
    for (int cg = 0; cg < 4; ++cg) {
      s8 bf = *(const s8*)(WT + ((wave << 6) + (cg << 4) + lr) * 256 + ks * 32 + lc * 8);
      acc[cg] = __builtin_amdgcn_mfma_f32_16x16x32_bf16(af, bf, acc[cg], 0, 0, 0);
    }
  }
  float p1[4] = {0, 0, 0, 0}, p2[4] = {0, 0, 0, 0};
  #pragma unroll
  for (int cg = 0; cg < 4; ++cg) {
    float a1v = a[wave * 128 + (cg << 4) + lr];
    float a2v = a[wave * 128 + 64 + (cg << 4) + lr];
    #pragma unroll
    for (int q = 0; q < 4; ++q) {
      p1[q] = fmaf(acc[cg][q], a1v, p1[q]);
      p2[q] = fmaf(acc[cg][q], a2v, p2[q]);
    }
  }
  #pragma unroll
  for (int m = 1; m <= 8; m <<= 1) {
    #pragma unroll
    for (int q = 0; q < 4; ++q) {
      p1[q] += __shfl_xor(p1[q], m, 64);
      p2[q] += __shfl_xor(p2[q], m, 64);
    }
  }
  if (lr == 0) {
    #pragma unroll
    for (int q = 0; q < 4; ++q) {
      f1[wave * N + i0 + (lc << 2) + q] = p1[q];
      f2[wave * N + i0 + (lc << 2) + q] = p2[q];
    }
  }
  float wm = fmaxf(fmaxf(p2[0], p2[1]), fmaxf(p2[2], p2[3]));
  wm = fmaxf(wm, __shfl_xor(wm, 16, 64));
  wm = fmaxf(wm, __shfl_xor(wm, 32, 64));
  if (lane == 0) atomicMax(&f2mkey[wave], fkey(wm));
  int b0 = (i0 & 31) + (lc << 2);
  int hi = b0 >> 3, e0 = b0 & 7;
  size_t cbase = ((size_t)(wave * 32 + (i0 >> 7)) * 4 + ((i0 >> 5) & 3)) << 2;
  #pragma unroll
  for (int cg = 0; cg < 4; ++cg) {
    union { uint16_t u[4]; s4 v; } h4;
    #pragma unroll
    for (int q = 0; q < 4; ++q) h4.u[q] = bf16_rne(acc[cg][q]);
    *(s4*)(hTf + ((cbase + cg) << 9) + ((hi << 4) + lr) * 8 + e0) = h4.v;
  }
}

// -------- K4: flash partial. NP=16, 32-row blocks, 32-j tiles, ------------
// -------- exp2-free select inner loop from precomputed A/E tables ---------
__global__ __launch_bounds__(256, 5) void k_attn(
    const int* __restrict__ adj, const float* __restrict__ f1,
    const float* __restrict__ f2, const uint32_t* __restrict__ f2mkey,
    const uint16_t* __restrict__ hTf,
    uint16_t* __restrict__ Op, float* __restrict__ lp) {
  const int N = 4096;
  __shared__ int   adjs[2][32][32];   // 8 KB double-buffered adj tile
  __shared__ float E1s[4][256];       // 4 KB  exp(f2_j) per head (partition slice)
  __shared__ float E2s[4][256];       // 4 KB  exp(0.2*f2_j)
  int p  = blockIdx.x & 15;           // partition; XCD = blockIdx&7 hosts {p, p+8}
  int rb = blockIdx.x >> 4;
  int i0 = rb << 5;                   // 32 rows
  int jbase = p << 8;                 // 256 j per partition
  const int ntiles = 8;               // 256 / 32
  int t = threadIdx.x, wave = t >> 6, lane = t & 63, lr = lane & 15, lc = lane >> 4;

  float fm = unkey(f2mkey[wave]);
  float a1f[2], a2f[2], Ti[2], lsum[2] = {0.f, 0.f};
  #pragma unroll
  for (int g = 0; g < 2; ++g) {
    float f1v = f1[wave * N + i0 + (g << 4) + lr];
    float s = f1v + fm;
    float M = fmaxf(s, 0.2f * s);          // static per-row upper bound
    a1f[g] = EXP2F((f1v - M) * LOG2E);     // branch s>=0 row factor
    a2f[g] = EXP2F(fmaf(f1v, LOG2E5, -M * LOG2E));  // branch s<0 row factor
    Ti[g]  = EXP2F(-f1v * LOG2E);          // threshold: s>=0 <=> E1_j >= Ti
  }
  {  // E tables: 256 j per head, 4 j per lane
    int j0 = lane << 2;
    f4 fv = *(const f4*)(f2 + wave * N + jbase + j0);
    f4 e1, e2;
    #pragma unroll
    for (int k = 0; k < 4; ++k) {
      e1[k] = EXP2F(fv[k] * LOG2E);
      e2[k] = EXP2F(fv[k] * LOG2E5);
    }
    *(f4*)&E1s[wave][j0] = e1;
    *(f4*)&E2s[wave][j0] = e2;
  }

  f4 acc[2][4];
  #pragma unroll
  for (int g = 0; g < 2; ++g)
    #pragma unroll
    for (int cg = 0; cg < 4; ++cg) acc[g][cg] = (f4){0.f, 0.f, 0.f, 0.f};

  // staging: 1 DMA inst/wave/tile. wave w stages rows 8w..8w+7 (8 x 128 B).
  int srow  = lane >> 3;                        // row-in-group 0..7
  int sslot = (lane & 7) ^ srow;                // xor-swizzled source chunk
  const int* gbase = adj + (size_t)(i0 + (wave << 3) + srow) * N + jbase + (sslot << 2);

  #define STAGE(TILE, BUF)                                                  \
    __builtin_amdgcn_global_load_lds(                                       \
        (const __attribute__((address_space(1))) void*)(gbase + ((TILE) << 5)), \
        (__attribute__((address_space(3))) void*)&adjs[BUF][wave << 3][0],  \
        16, 0, 0);

  STAGE(0, 0);
  __syncthreads();   // covers E-table writes + first adj tile

  // hTf chunk = wave*512 + (p*8 + tile)*4 + cg ; 512 shorts/chunk
  const uint16_t* hTfb = hTf + ((size_t)(wave * 512 + p * 32) << 9) + lane * 8;

  for (int tile = 0;; ++tile) {
    int cur = tile & 1;
    if (tile + 1 < ntiles) STAGE(tile + 1, cur ^ 1);
    const uint16_t* hTft = hTfb + ((size_t)tile << 11);
    s8 bf0 = *(const s8*)(hTft);
    s8 bf1 = *(const s8*)(hTft + 512);
    s8 bf2v = *(const s8*)(hTft + 1024);
    s8 bf3 = *(const s8*)(hTft + 1536);
    int jo = (tile << 5) + (lc << 3);
    f4 E1a = *(const f4*)&E1s[wave][jo];
    f4 E1b = *(const f4*)&E1s[wave][jo + 4];
    f4 E2a = *(const f4*)&E2s[wave][jo];
    f4 E2b = *(const f4*)&E2s[wave][jo + 4];
    #pragma unroll
    for (int g = 0; g < 2; ++g) {
      const i4* rowp = (const i4*)&adjs[cur][(g << 4) + lr][0];
      int sw = lr & 7;
      i4 a0 = rowp[(lc << 1) ^ sw];
      i4 a1v = rowp[((lc << 1) + 1) ^ sw];
      uint32_t eb[8];
      #pragma unroll
      for (int e = 0; e < 8; ++e) {
        float e1 = (e < 4) ? E1a[e] : E1b[e - 4];
        float e2 = (e < 4) ? E2a[e] : E2b[e - 4];
        int   ai = (e < 4) ? a0[e]  : a1v[e - 4];
        bool  c  = e1 >= Ti[g];
        float pf = (c ? a1f[g] : a2f[g]) * (c ? e1 : e2);
        uint32_t mb = fbits(pf) & (uint32_t)(-ai);   // adj mask
        lsum[g] += ubits(mb);
        eb[e] = mb + 0x8000u;                        // bf16 round-half-up
      }
      union { uint32_t u[4]; s8 v; } af;
      #pragma unroll
      for (int i2 = 0; i2 < 4; ++i2)
        af.u[i2] = __builtin_amdgcn_perm(eb[2 * i2 + 1], eb[2 * i2], 0x07060302u);
      acc[g][0] = __builtin_amdgcn_mfma_f32_16x16x32_bf16(af.v, bf0, acc[g][0], 0, 0, 0);
      acc[g][1] = __builtin_amdgcn_mfma_f32_16x16x32_bf16(af.v, bf1, acc[g][1], 0, 0, 0);
      acc[g][2] = __builtin_amdgcn_mfma_f32_16x16x32_bf16(af.v, bf2v, acc[g][2], 0, 0, 0);
      acc[g][3] = __builtin_amdgcn_mfma_f32_16x16x32_bf16(af.v, bf3, acc[g][3], 0, 0, 0);
    }
    if (tile + 1 >= ntiles) break;
    __syncthreads();
  }
  #undef STAGE

  // store partials
  uint16_t* ob = Op + (size_t)((p << 2) + wave) * N * 64 + (size_t)i0 * 64;
  #pragma unroll
  for (int g = 0; g < 2; ++g) {
    #pragma unroll
    for (int cg = 0; cg < 4; ++cg) {
      #pragma unroll
      for (int q = 0; q < 4; ++q)
        ob[((g << 4) + (lc << 2) + q) * 64 + (cg << 4) + lr] = bf16_rne(acc[g][cg][q]);
    }
    float v = lsum[g];
    v += __shfl_xor(v, 16, 64);
    v += __shfl_xor(v, 32, 64);
    if (lane < 16) lp[(size_t)((p << 2) + wave) * N + i0 + (g << 4) + lane] = v;
  }
}

// ---------------- K5: out = sum_p O_p / sum_p l_p (8 outs/thread) ----------
__global__ __launch_bounds__(256) void k_combine(
    const uint16_t* __restrict__ Op, const float* __restrict__ lp,
    float* __restrict__ out, int NP) {
  int idx = blockIdx.x * 256 + threadIdx.x;   // 131072 threads, 8 f32 each
  int n = idx >> 5;
  int c8 = (idx & 31) << 3;
  int h = c8 >> 6, o = c8 & 63;
  float s[8] = {0, 0, 0, 0, 0, 0, 0, 0};
  float ls = 0.f;
  for (int p = 0; p < NP; ++p) {
    size_t base = (size_t)((p << 2) + h) * 4096 + n;
    s8 v = *(const s8*)(Op + base * 64 + o);
    #pragma unroll
    for (int k = 0; k < 8; ++k) s[k] += bf2f((uint16_t)v[k]);
    ls += lp[base];
  }
  float inv = (ls > 0.f) ? 1.0f / ls : 0.f;
  f4 r0 = {s[0] * inv, s[1] * inv, s[2] * inv, s[3] * inv};
  f4 r1 = {s[4] * inv, s[5] * inv, s[6] * inv, s[7] * inv};
  float* dst = out + (size_t)n * 256 + c8;
  *(f4*)dst = r0;
  *(f4*)(dst + 4) = r1;
}

extern "C" void kernel_launch(void* const* d_in, const int* in_sizes, int n_in,
                              void* d_out, int out_size, void* d_ws, size_t ws_size,
                              hipStream_t stream) {
  (void)in_sizes; (void)n_in; (void)out_size; (void)ws_size;
  const float* x   = (const float*)d_in[0];
  const int*   adj = (const int*)d_in[1];
  const float* W   = (const float*)d_in[2];
  const float* a   = (const float*)d_in[3];
  float* out = (float*)d_out;
  char* ws = (char*)d_ws;

  const int NP = 16;
  size_t oWT = 0;
  size_t oHT = oWT + 131072;       // WT : 4*64*256*2
  size_t oF1 = oHT + 2097152;      // hTf: 4*64*4096*2 (fragment order)
  size_t oF2 = oF1 + 65536;        // f1 : 4*4096*4
  size_t oFM = oF2 + 65536;        // f2
  size_t oOP = (oFM + 16 + 255) & ~(size_t)255;
  size_t oLP = oOP + (size_t)NP * 2097152;   // Op: NP*4*4096*64*2 = 33.5 MB

  uint16_t* WT   = (uint16_t*)(ws + oWT);
  uint16_t* hTf  = (uint16_t*)(ws + oHT);
  float*    f1   = (float*)(ws + oF1);
  float*    f2   = (float*)(ws + oF2);
  uint32_t* f2mk = (uint32_t*)(ws + oFM);
  uint16_t* Op   = (uint16_t*)(ws + oOP);
  float*    lp   = (float*)(ws + oLP);

  k_prep_wt<<<64, 256, 0, stream>>>(W, WT, f2mk);
  k_gemm_h<<<256, 256, 0, stream>>>(x, WT, a, hTf, f1, f2, f2mk);
  k_attn<<<128 * NP, 256, 0, stream>>>(adj, f1, f2, f2mk, hTf, Op, lp);
  k_combine<<<512, 256, 0, stream>>>(Op, lp, out, NP);
}

// Round 5
// 77.447 us; speedup vs baseline: 1.3497x; 1.3497x over previous
//
#include <hip/hip_runtime.h>
#include <hip/hip_bf16.h>
#include <stdint.h>

#define LOG2E  1.4426950408889634f
#define LOG2E5 0.28853900817779268f   // 0.2 * LOG2E

typedef __attribute__((ext_vector_type(4))) float f4;
typedef __attribute__((ext_vector_type(4))) int   i4;
typedef __attribute__((ext_vector_type(8))) short s8;   // 8 x bf16
typedef __attribute__((ext_vector_type(4))) short s4;   // 4 x bf16

#if defined(__has_builtin)
# if __has_builtin(__builtin_amdgcn_exp2f)
#  define EXP2F(x) __builtin_amdgcn_exp2f(x)
# else
#  define EXP2F(x) exp2f(x)
# endif
#else
# define EXP2F(x) exp2f(x)
#endif

static __device__ __forceinline__ uint32_t fbits(float f) {
  union { float f; uint32_t u; } c; c.f = f; return c.u;
}
static __device__ __forceinline__ float ubits(uint32_t u) {
  union { uint32_t u; float f; } c; c.u = u; return c.f;
}
static __device__ __forceinline__ uint16_t bf16_rne(float f) {
  uint32_t b = fbits(f);
  b += 0x7FFFu + ((b >> 16) & 1u);
  return (uint16_t)(b >> 16);
}
static __device__ __forceinline__ float bf2f(uint16_t u) {
  return ubits(((uint32_t)u) << 16);
}
static __device__ __forceinline__ uint32_t fkey(float f) {
  uint32_t u = fbits(f);
  return (u >> 31) ? ~u : (u | 0x80000000u);
}
static __device__ __forceinline__ float unkey(uint32_t k) {
  return ubits((k & 0x80000000u) ? (k ^ 0x80000000u) : ~k);
}

// ---- K0: adj (4096x4096 int) -> bitsT[chunk][row], bit j%32 of chunk j/32 --
__global__ __launch_bounds__(256) void k_pack(const int* __restrict__ adj,
                                              uint32_t* __restrict__ bitsT) {
  int gw = (blockIdx.x * 256 + threadIdx.x) >> 6;   // 8192 waves
  int lane = threadIdx.x & 63;
  for (int task = gw; task < 262144; task += 8192) {     // 32 iters/wave
    int r = task >> 6, cp = task & 63;                   // row, 64-col group
    int v = adj[((size_t)r << 12) + (cp << 6) + lane];
    uint64_t b = __ballot(v != 0);
    if (lane == 0)  bitsT[(size_t)(cp * 2 + 0) * 4096 + r] = (uint32_t)b;
    if (lane == 32) bitsT[(size_t)(cp * 2 + 1) * 4096 + r] = (uint32_t)(b >> 32);
  }
}

// ---- K1: W (H,256,64) f32 -> WT (H,64,256) bf16; init f2max keys ----
__global__ __launch_bounds__(256) void k_prep_wt(const float* __restrict__ W,
                                                 uint16_t* __restrict__ WT,
                                                 uint32_t* __restrict__ f2mkey) {
  if (blockIdx.x == 0 && threadIdx.x < 4) f2mkey[threadIdx.x] = 0u;
  int idx = (blockIdx.x * 256 + threadIdx.x) * 4;
  f4 w = *(const f4*)(W + idx);
  int h = idx >> 14;
  int k = (idx >> 6) & 255;
  int o = idx & 63;
  uint16_t* base = WT + ((h << 6) + o) * 256 + k;
  base[0]   = bf16_rne(w.x);
  base[256] = bf16_rne(w.y);
  base[512] = bf16_rne(w.z);
  base[768] = bf16_rne(w.w);
}

// ------- K2: h = x @ W per head (MFMA), fused f1/f2 + f2max ---------------
// hTf chunk = h*512 + (j/32)*4 + cg, 512 shorts/chunk (B-fragment order).
__global__ __launch_bounds__(256) void k_gemm_h(
    const float* __restrict__ x, const uint16_t* __restrict__ WT,
    const float* __restrict__ a,
    uint16_t* __restrict__ hTf, float* __restrict__ f1, float* __restrict__ f2,
    uint32_t* __restrict__ f2mkey) {
  const int N = 4096, K = 256;
  __shared__ uint16_t xs[16][264];
  int t = threadIdx.x;
  int i0 = blockIdx.x * 16;
  {
    int r = t >> 4, c = (t & 15) << 4;
    const float* src = x + (i0 + r) * K + c;
    union { uint16_t u[16]; s8 v[2]; } tmp;
    #pragma unroll
    for (int i = 0; i < 16; i += 4) {
      f4 v = *(const f4*)(src + i);
      tmp.u[i+0] = bf16_rne(v.x); tmp.u[i+1] = bf16_rne(v.y);
      tmp.u[i+2] = bf16_rne(v.z); tmp.u[i+3] = bf16_rne(v.w);
    }
    *(s8*)&xs[r][c]     = tmp.v[0];
    *(s8*)&xs[r][c + 8] = tmp.v[1];
  }
  __syncthreads();
  int wave = t >> 6, lane = t & 63, lr = lane & 15, lc = lane >> 4;
  f4 acc[4];
  #pragma unroll
  for (int cg = 0; cg < 4; ++cg) acc[cg] = (f4){0.f, 0.f, 0.f, 0.f};
  #pragma unroll
  for (int ks = 0; ks < 8; ++ks) {
    s8 af = *(const s8*)&xs[lr][ks * 32 + lc * 8];
    #pragma unroll
    for (int cg = 0; cg < 4; ++cg) {
      s8 bf = *(const s8*)(WT + ((wave << 6) + (cg << 4) + lr) * 256 + ks * 32 + lc * 8);
      acc[cg] = __builtin_amdgcn_mfma_f32_16x16x32_bf16(af, bf, acc[cg], 0, 0, 0);
    }
  }
  float p1[4] = {0, 0, 0, 0}, p2[4] = {0, 0, 0, 0};
  #pragma unroll
  for (int cg = 0; cg < 4; ++cg) {
    float a1v = a[wave * 128 + (cg << 4) + lr];
    float a2v = a[wave * 128 + 64 + (cg << 4) + lr];
    #pragma unroll
    for (int q = 0; q < 4; ++q) {
      p1[q] = fmaf(acc[cg][q], a1v, p1[q]);
      p2[q] = fmaf(acc[cg][q], a2v, p2[q]);
    }
  }
  #pragma unroll
  for (int m = 1; m <= 8; m <<= 1) {
    #pragma unroll
    for (int q = 0; q < 4; ++q) {
      p1[q] += __shfl_xor(p1[q], m, 64);
      p2[q] += __shfl_xor(p2[q], m, 64);
    }
  }
  if (lr == 0) {
    #pragma unroll
    for (int q = 0; q < 4; ++q) {
      f1[wave * N + i0 + (lc << 2) + q] = p1[q];
      f2[wave * N + i0 + (lc << 2) + q] = p2[q];
    }
  }
  float wm = fmaxf(fmaxf(p2[0], p2[1]), fmaxf(p2[2], p2[3]));
  wm = fmaxf(wm, __shfl_xor(wm, 16, 64));
  wm = fmaxf(wm, __shfl_xor(wm, 32, 64));
  if (lane == 0) atomicMax(&f2mkey[wave], fkey(wm));
  int b0 = (i0 & 31) + (lc << 2);
  int hi = b0 >> 3, e0 = b0 & 7;
  size_t cbase = ((size_t)(wave * 32 + (i0 >> 7)) * 4 + ((i0 >> 5) & 3)) << 2;
  #pragma unroll
  for (int cg = 0; cg < 4; ++cg) {
    union { uint16_t u[4]; s4 v; } h4;
    #pragma unroll
    for (int q = 0; q < 4; ++q) h4.u[q] = bf16_rne(acc[cg][q]);
    *(s4*)(hTf + ((cbase + cg) << 9) + ((hi << 4) + lr) * 8 + e0) = h4.v;
  }
}

// -------- K4: flash partial from bitmask. No LDS, no barriers. ------------
// wave = head, 32 rows/block, 256-j slice (NP=16), straight-line 8 chunks.
__global__ __launch_bounds__(256, 4) void k_attn(
    const uint32_t* __restrict__ bitsT, const float* __restrict__ f1,
    const float* __restrict__ f2, const uint32_t* __restrict__ f2mkey,
    const uint16_t* __restrict__ hTf,
    uint16_t* __restrict__ Op, float* __restrict__ lp) {
  const int N = 4096;
  int p  = blockIdx.x & 15;           // j-partition (256 cols each)
  int rb = blockIdx.x >> 4;
  int i0 = rb << 5;                   // 32 rows
  int jbase = p << 8;
  int t = threadIdx.x, wave = t >> 6, lane = t & 63, lr = lane & 15, lc = lane >> 4;

  float fm = unkey(f2mkey[wave]);
  float d1[2], d2[2];
  #pragma unroll
  for (int g = 0; g < 2; ++g) {
    float f1v = f1[wave * N + i0 + (g << 4) + lr];
    float s = f1v + fm;
    float M = fmaxf(s, 0.2f * s);          // static per-row upper bound
    d1[g] = fmaf(f1v, LOG2E, -M * LOG2E);
    d2[g] = fmaf(f1v, LOG2E5, -M * LOG2E);
  }
  f4 acc[2][4], accl[2];
  #pragma unroll
  for (int g = 0; g < 2; ++g) {
    accl[g] = (f4){0.f, 0.f, 0.f, 0.f};
    #pragma unroll
    for (int cg = 0; cg < 4; ++cg) acc[g][cg] = (f4){0.f, 0.f, 0.f, 0.f};
  }
  const s8 ones = {0x3F80, 0x3F80, 0x3F80, 0x3F80, 0x3F80, 0x3F80, 0x3F80, 0x3F80};

  const uint32_t* bwp = bitsT + ((size_t)(p << 3) << 12) + i0 + lr;  // +chunk*4096
  const float* f2b = f2 + wave * N + jbase + (lc << 3);
  // hTf chunk = wave*512 + (p*8+c)*4 + cg ; 512 shorts (1 KB) per chunk
  const uint16_t* hTfb = hTf + ((size_t)(wave * 512 + p * 32) << 9) + lane * 8;
  int sh = lc << 3;

  #pragma unroll
  for (int c = 0; c < 8; ++c) {
    uint32_t ws0 = bwp[c << 12] >> sh;            // bits for row g=0, this chunk
    uint32_t ws1 = bwp[(c << 12) + 16] >> sh;     // row g=1
    f4 f2v0 = *(const f4*)(f2b + (c << 5));
    f4 f2v1 = *(const f4*)(f2b + (c << 5) + 4);
    s8 bf0 = *(const s8*)(hTfb + ((c << 2) << 9));
    s8 bf1 = *(const s8*)(hTfb + (((c << 2) + 1) << 9));
    s8 bf2v = *(const s8*)(hTfb + (((c << 2) + 2) << 9));
    s8 bf3 = *(const s8*)(hTfb + (((c << 2) + 3) << 9));
    #pragma unroll
    for (int g = 0; g < 2; ++g) {
      uint32_t ws = g ? ws1 : ws0;
      uint32_t eb[8];
      #pragma unroll
      for (int e = 0; e < 8; ++e) {
        float f2e = (e < 4) ? f2v0[e] : f2v1[e - 4];
        float arg = fmaxf(fmaf(f2e, LOG2E, d1[g]),
                          fmaf(f2e, LOG2E5, d2[g]));
        uint32_t msk = 0u - ((ws >> e) & 1u);
        eb[e] = (fbits(EXP2F(arg)) & msk) + 0x8000u;   // mask + round-half-up
      }
      union { uint32_t u[4]; s8 v; } af;
      #pragma unroll
      for (int i2 = 0; i2 < 4; ++i2)
        af.u[i2] = __builtin_amdgcn_perm(eb[2 * i2 + 1], eb[2 * i2], 0x07060302u);
      acc[g][0] = __builtin_amdgcn_mfma_f32_16x16x32_bf16(af.v, bf0, acc[g][0], 0, 0, 0);
      acc[g][1] = __builtin_amdgcn_mfma_f32_16x16x32_bf16(af.v, bf1, acc[g][1], 0, 0, 0);
      acc[g][2] = __builtin_amdgcn_mfma_f32_16x16x32_bf16(af.v, bf2v, acc[g][2], 0, 0, 0);
      acc[g][3] = __builtin_amdgcn_mfma_f32_16x16x32_bf16(af.v, bf3, acc[g][3], 0, 0, 0);
      accl[g]   = __builtin_amdgcn_mfma_f32_16x16x32_bf16(af.v, ones, accl[g], 0, 0, 0);
    }
  }

  // store partials
  uint16_t* ob = Op + (size_t)((p << 2) + wave) * N * 64 + (size_t)i0 * 64;
  #pragma unroll
  for (int g = 0; g < 2; ++g) {
    #pragma unroll
    for (int cg = 0; cg < 4; ++cg) {
      #pragma unroll
      for (int q = 0; q < 4; ++q)
        ob[((g << 4) + (lc << 2) + q) * 64 + (cg << 4) + lr] = bf16_rne(acc[g][cg][q]);
    }
    if (lr == 0) {
      #pragma unroll
      for (int q = 0; q < 4; ++q)
        lp[(size_t)((p << 2) + wave) * N + i0 + (g << 4) + (lc << 2) + q] = accl[g][q];
    }
  }
}

// ---------------- K5: out = sum_p O_p / sum_p l_p (8 outs/thread) ----------
__global__ __launch_bounds__(256) void k_combine(
    const uint16_t* __restrict__ Op, const float* __restrict__ lp,
    float* __restrict__ out, int NP) {
  int idx = blockIdx.x * 256 + threadIdx.x;
  int n = idx >> 5;
  int c8 = (idx & 31) << 3;
  int h = c8 >> 6, o = c8 & 63;
  float s[8] = {0, 0, 0, 0, 0, 0, 0, 0};
  float ls = 0.f;
  for (int p = 0; p < NP; ++p) {
    size_t base = (size_t)((p << 2) + h) * 4096 + n;
    s8 v = *(const s8*)(Op + base * 64 + o);
    #pragma unroll
    for (int k = 0; k < 8; ++k) s[k] += bf2f((uint16_t)v[k]);
    ls += lp[base];
  }
  float inv = (ls > 0.f) ? 1.0f / ls : 0.f;
  f4 r0 = {s[0] * inv, s[1] * inv, s[2] * inv, s[3] * inv};
  f4 r1 = {s[4] * inv, s[5] * inv, s[6] * inv, s[7] * inv};
  float* dst = out + (size_t)n * 256 + c8;
  *(f4*)dst = r0;
  *(f4*)(dst + 4) = r1;
}

extern "C" void kernel_launch(void* const* d_in, const int* in_sizes, int n_in,
                              void* d_out, int out_size, void* d_ws, size_t ws_size,
                              hipStream_t stream) {
  (void)in_sizes; (void)n_in; (void)out_size; (void)ws_size;
  const float* x   = (const float*)d_in[0];
  const int*   adj = (const int*)d_in[1];
  const float* W   = (const float*)d_in[2];
  const float* a   = (const float*)d_in[3];
  float* out = (float*)d_out;
  char* ws = (char*)d_ws;

  const int NP = 16;
  size_t oWT = 0;
  size_t oHT = oWT + 131072;       // WT : 4*64*256*2
  size_t oF1 = oHT + 2097152;      // hTf: 4*64*4096*2 (fragment order)
  size_t oF2 = oF1 + 65536;        // f1 : 4*4096*4
  size_t oFM = oF2 + 65536;        // f2
  size_t oBT = (oFM + 16 + 255) & ~(size_t)255;
  size_t oOP = oBT + 2097152;      // bitsT: 128*4096*4 = 2 MB
  size_t oLP = oOP + (size_t)NP * 2097152;   // Op: NP*4*4096*64*2

  uint16_t* WT    = (uint16_t*)(ws + oWT);
  uint16_t* hTf   = (uint16_t*)(ws + oHT);
  float*    f1    = (float*)(ws + oF1);
  float*    f2    = (float*)(ws + oF2);
  uint32_t* f2mk  = (uint32_t*)(ws + oFM);
  uint32_t* bitsT = (uint32_t*)(ws + oBT);
  uint16_t* Op    = (uint16_t*)(ws + oOP);
  float*    lp    = (float*)(ws + oLP);

  k_pack<<<2048, 256, 0, stream>>>(adj, bitsT);
  k_prep_wt<<<64, 256, 0, stream>>>(W, WT, f2mk);
  k_gemm_h<<<256, 256, 0, stream>>>(x, WT, a, hTf, f1, f2, f2mk);
  k_attn<<<128 * NP, 256, 0, stream>>>(bitsT, f1, f2, f2mk, hTf, Op, lp);
  k_combine<<<512, 256, 0, stream>>>(Op, lp, out, NP);
}